// Round 3
// baseline (1386.591 us; speedup 1.0000x reference)
//
#include <hip/hip_runtime.h>
#include <stdint.h>

// GraphConv: out = indeg^-1/2 * segsum_dst( (feat * outdeg^-1/2)[src] ) @ W
// Transform-first (linearity): h = (feat*outdeg^-1/2) @ W once, then
// aggregate h rows per dst.
//
// R3: global-atomic elimination. Measured memory-side atomic rate ~26G/s
// made 3.2M atomics a 125us floor. Replaced by two-level partitioning:
// edges are binned into 1563 fixed-capacity dst-partitions (64 nodes each)
// with LDS-atomic ranking + ~400k bulk global reservations; out-degree via
// partitioned src bytes + LDS histograms. Aggregation fuses gather (bf16,
// lane-permuted h), in-degree count, scaling and store per partition.

#define DIM 128
#define PN 64            // nodes per partition
#define MAXP 1568        // >= ceil(100000/64)=1563
#define CAPE 1536        // edges per dst-partition; mean 1024, +16 sigma
#define CAPS 1536        // src entries per src-partition
#define NB_PART 128

typedef unsigned int uint;
typedef unsigned short ushortT;

__device__ __forceinline__ ushortT f2bf(float x) {
    uint u = __float_as_uint(x);
    u = (u + 0x7FFFu + ((u >> 16) & 1u)) >> 16;   // RNE
    return (ushortT)u;
}
__device__ __forceinline__ float bf2f(ushortT b) {
    return __uint_as_float(((uint)b) << 16);
}

// ---------------- part: bin edges by dst>>6, src bytes by src>>6 ------------
__global__ __launch_bounds__(256) void part(
    const int* __restrict__ src, const int* __restrict__ dst,
    int* __restrict__ curD, int* __restrict__ curS,
    int* __restrict__ pairs, unsigned char* __restrict__ srcb,
    int E, int NP, int chunk) {
    __shared__ int cD[MAXP];
    __shared__ int cS[MAXP];
    int tid = threadIdx.x;
    int e0 = blockIdx.x * chunk;
    int e1 = min(E, e0 + chunk);
    for (int i = tid; i < NP; i += 256) { cD[i] = 0; cS[i] = 0; }
    __syncthreads();
    // phase 1: local counts (LDS atomics)
    for (int e = e0 + tid; e < e1; e += 256) {
        int d = dst[e], s = src[e];
        atomicAdd(&cD[d >> 6], 1);
        atomicAdd(&cS[s >> 6], 1);
    }
    __syncthreads();
    // phase 2: bulk reservation (few global atomics), cursor := my base
    for (int b = tid; b < NP; b += 256) {
        int c = cD[b];
        cD[b] = c ? atomicAdd(&curD[b], c) : 0;
        c = cS[b];
        cS[b] = c ? atomicAdd(&curS[b], c) : 0;
    }
    __syncthreads();
    // phase 3: re-rank via LDS cursors, scatter into exact slots
    for (int e = e0 + tid; e < e1; e += 256) {
        int d = dst[e], s = src[e];
        int pd = d >> 6, ps = s >> 6;
        int slot = atomicAdd(&cD[pd], 1);
        if (slot < CAPE) pairs[pd * CAPE + slot] = (s << 6) | (d & 63);
        int slot2 = atomicAdd(&cS[ps], 1);
        if (slot2 < CAPS) srcb[(size_t)ps * CAPS + slot2] = (unsigned char)(s & 63);
    }
}

// ---------------- deg: per-partition out-degree histogram -> oscale ---------
__global__ __launch_bounds__(256) void deg(
    const int* __restrict__ curS, const unsigned char* __restrict__ srcb,
    float* __restrict__ oscale, int N) {
    __shared__ int hist[PN];
    int p = blockIdx.x, tid = threadIdx.x;
    if (tid < PN) hist[tid] = 0;
    __syncthreads();
    int cnt = min(curS[p], CAPS);
    const unsigned char* b = &srcb[(size_t)p * CAPS];
    for (int i = tid; i < cnt; i += 256) atomicAdd(&hist[b[i]], 1);
    __syncthreads();
    if (tid < PN) {
        int node = p * PN + tid;
        if (node < N) oscale[node] = rsqrtf((float)max(hist[tid], 1));
    }
}

// ---------------- h = (feat * outdeg^-1/2) @ W  (bf16, lane-permuted) -------
// 32 rows x 128 cols per block, 256 threads, 4x4 per thread, BK=32.
// h row layout: position 4*l+k holds element l+32k (l=0..31,k=0..3), so the
// agg kernel's ushort4-gather lane l maps to LDS banks == lane (conflict-free).
__global__ __launch_bounds__(256) void gemm_h(
    const float* __restrict__ feat, const float* __restrict__ W,
    const float* __restrict__ oscale, ushortT* __restrict__ h, int M) {
    __shared__ float As[32][36];
    __shared__ float Bs[32][128];

    int tid = threadIdx.x;
    int m0 = blockIdx.x * 32;
    int tx = tid & 31;
    int ty = tid >> 5;
    int bc = tx << 2;

    float acc[4][4];
#pragma unroll
    for (int r = 0; r < 4; ++r)
#pragma unroll
        for (int c = 0; c < 4; ++c) acc[r][c] = 0.f;

    int am = tid >> 3;
    int ak = (tid & 7) << 2;
    int arow = m0 + am;
    float scale = (arow < M) ? oscale[arow] : 0.f;

    for (int k0 = 0; k0 < DIM; k0 += 32) {
        float4 a = make_float4(0.f, 0.f, 0.f, 0.f);
        if (arow < M) a = *(const float4*)&feat[(size_t)arow * DIM + k0 + ak];
        As[ak + 0][am] = a.x * scale;
        As[ak + 1][am] = a.y * scale;
        As[ak + 2][am] = a.z * scale;
        As[ak + 3][am] = a.w * scale;
#pragma unroll
        for (int i = 0; i < 4; ++i) {
            int k = ty + i * 8;
            *(float4*)&Bs[k][bc] = *(const float4*)&W[(size_t)(k0 + k) * DIM + bc];
        }
        __syncthreads();
#pragma unroll
        for (int k = 0; k < 32; ++k) {
            float4 a4 = *(const float4*)&As[k][ty << 2];
            float4 b4 = *(const float4*)&Bs[k][bc];
            acc[0][0] += a4.x * b4.x; acc[0][1] += a4.x * b4.y; acc[0][2] += a4.x * b4.z; acc[0][3] += a4.x * b4.w;
            acc[1][0] += a4.y * b4.x; acc[1][1] += a4.y * b4.y; acc[1][2] += a4.y * b4.z; acc[1][3] += a4.y * b4.w;
            acc[2][0] += a4.z * b4.x; acc[2][1] += a4.z * b4.y; acc[2][2] += a4.z * b4.z; acc[2][3] += a4.z * b4.w;
            acc[3][0] += a4.w * b4.x; acc[3][1] += a4.w * b4.y; acc[3][2] += a4.w * b4.z; acc[3][3] += a4.w * b4.w;
        }
        __syncthreads();
    }
    // epilogue: stage tile in LDS (reuse Bs), emit bf16 permuted rows
    float* T = &Bs[0][0];
#pragma unroll
    for (int r = 0; r < 4; ++r)
#pragma unroll
        for (int j = 0; j < 4; ++j)
            T[((ty << 2) + r) * 128 + bc + j] = acc[r][j];
    __syncthreads();
    for (int q = tid; q < 1024; q += 256) {
        int row = q >> 5, l = q & 31;
        int m = m0 + row;
        if (m < M) {
            ushort4 v;
            v.x = f2bf(T[row * 128 + l]);
            v.y = f2bf(T[row * 128 + l + 32]);
            v.z = f2bf(T[row * 128 + l + 64]);
            v.w = f2bf(T[row * 128 + l + 96]);
            *(ushort4*)&h[(size_t)m * DIM + (l << 2)] = v;
        }
    }
}

// ---------------- agg: fused gather + indeg + scale + store -----------------
// One block per dst-partition: 64 fp32 rows in LDS; half-wave per edge.
__global__ __launch_bounds__(256) void agg(
    const ushortT* __restrict__ h, const int* __restrict__ pairs,
    const int* __restrict__ curD, float* __restrict__ out, int N) {
    __shared__ float rows[PN * DIM];   // 32 KB
    __shared__ float isc[PN];
    __shared__ int cntL[PN];
    int p = blockIdx.x, tid = threadIdx.x;
    for (int i = tid; i < PN * DIM; i += 256) rows[i] = 0.f;
    if (tid < PN) cntL[tid] = 0;
    __syncthreads();
    int cnt = min(curD[p], CAPE);
    const int* pb = &pairs[(size_t)p * CAPE];
    int hw = tid >> 5, l = tid & 31;
    int e = hw;
    for (; e + 8 < cnt; e += 16) {
        int w0 = pb[e], w1 = pb[e + 8];
        int s0 = w0 >> 6, d0 = w0 & 63;
        int s1 = w1 >> 6, d1 = w1 & 63;
        ushort4 a = *(const ushort4*)&h[(size_t)s0 * DIM + (l << 2)];
        ushort4 b = *(const ushort4*)&h[(size_t)s1 * DIM + (l << 2)];
        if (l == 0) { atomicAdd(&cntL[d0], 1); atomicAdd(&cntL[d1], 1); }
        atomicAdd(&rows[d0 * DIM + l],      bf2f(a.x));
        atomicAdd(&rows[d0 * DIM + l + 32], bf2f(a.y));
        atomicAdd(&rows[d0 * DIM + l + 64], bf2f(a.z));
        atomicAdd(&rows[d0 * DIM + l + 96], bf2f(a.w));
        atomicAdd(&rows[d1 * DIM + l],      bf2f(b.x));
        atomicAdd(&rows[d1 * DIM + l + 32], bf2f(b.y));
        atomicAdd(&rows[d1 * DIM + l + 64], bf2f(b.z));
        atomicAdd(&rows[d1 * DIM + l + 96], bf2f(b.w));
    }
    for (; e < cnt; e += 8) {
        int w0 = pb[e];
        int s0 = w0 >> 6, d0 = w0 & 63;
        ushort4 a = *(const ushort4*)&h[(size_t)s0 * DIM + (l << 2)];
        if (l == 0) atomicAdd(&cntL[d0], 1);
        atomicAdd(&rows[d0 * DIM + l],      bf2f(a.x));
        atomicAdd(&rows[d0 * DIM + l + 32], bf2f(a.y));
        atomicAdd(&rows[d0 * DIM + l + 64], bf2f(a.z));
        atomicAdd(&rows[d0 * DIM + l + 96], bf2f(a.w));
    }
    __syncthreads();
    if (tid < PN) isc[tid] = rsqrtf((float)max(cntL[tid], 1));
    __syncthreads();
    int nb = p * PN;
    for (int i = tid << 2; i < PN * DIM; i += 1024) {
        int row = i >> 7;
        int node = nb + row;
        if (node < N) {
            float4 v = *(float4*)&rows[i];
            float s = isc[row];
            *(float4*)&out[(size_t)node * DIM + (i & 127)] =
                make_float4(v.x * s, v.y * s, v.z * s, v.w * s);
        }
    }
}

extern "C" void kernel_launch(void* const* d_in, const int* in_sizes, int n_in,
                              void* d_out, int out_size, void* d_ws, size_t ws_size,
                              hipStream_t stream) {
    const float* feat = (const float*)d_in[0];
    const float* W    = (const float*)d_in[1];
    const int*   src  = (const int*)d_in[2];
    const int*   dst  = (const int*)d_in[3];
    float* out = (float*)d_out;

    int N = in_sizes[0] / DIM;       // 100000
    int E = in_sizes[2];             // 1.6M
    int NP = (N + PN - 1) / PN;      // 1563 (<= MAXP)

    // workspace layout
    int* curD = (int*)d_ws;                       // NP
    int* curS = curD + NP;                        // NP
    float* oscale = (float*)(curS + NP);          // N
    int* pairs = (int*)(oscale + N);              // NP*CAPE
    unsigned char* srcb = (unsigned char*)(pairs + (size_t)NP * CAPE);  // NP*CAPS
    uintptr_t hp = (uintptr_t)(srcb + (size_t)NP * CAPS);
    ushortT* h = (ushortT*)((hp + 15) & ~(uintptr_t)15);  // N*DIM bf16

    hipMemsetAsync(curD, 0, (size_t)2 * NP * sizeof(int), stream);

    int chunk = (E + NB_PART - 1) / NB_PART;
    part<<<NB_PART, 256, 0, stream>>>(src, dst, curD, curS, pairs, srcb, E, NP, chunk);
    deg<<<NP, 256, 0, stream>>>(curS, srcb, oscale, N);
    gemm_h<<<(N + 31) / 32, 256, 0, stream>>>(feat, W, oscale, h, N);
    agg<<<NP, 256, 0, stream>>>(h, pairs, curD, out, N);
}

// Round 4
// 284.100 us; speedup vs baseline: 4.8806x; 4.8806x over previous
//
#include <hip/hip_runtime.h>
#include <stdint.h>

// GraphConv: out = indeg^-1/2 * segsum_dst( (feat * outdeg^-1/2)[src] ) @ W
// Transform-first (linearity): h = (feat*outdeg^-1/2) @ W once (bf16,
// lane-permuted), then aggregate h rows per dst.
//
// R4: R3's agg regressed 7x -- LDS *float* atomics are ~per-lane serialized
// (~230 cyc/wave-instr measured; int LDS atomics are fine, cf. part).
// New aggp: per-partition in-LDS counting sort (int atomics only) ->
// dst-sorted src list -> REGISTER accumulation per node (half-wave), 4-deep
// unrolled bf16 gathers for memory-level parallelism. No fp atomics anywhere.

#define DIM 128
#define PN 64            // nodes per partition
#define MAXP 1568        // >= ceil(100000/64)=1563
#define CAPE 1536        // edges per dst-partition; mean 1024, +16 sigma
#define CAPS 1536        // src entries per src-partition
#define NB_PART 128
#define PULL_T 512

typedef unsigned int uint;
typedef unsigned short ushortT;

__device__ __forceinline__ ushortT f2bf(float x) {
    uint u = __float_as_uint(x);
    u = (u + 0x7FFFu + ((u >> 16) & 1u)) >> 16;   // RNE
    return (ushortT)u;
}
__device__ __forceinline__ float bf2f(ushortT b) {
    return __uint_as_float(((uint)b) << 16);
}

// ---------------- part: bin edges by dst>>6, src bytes by src>>6 ------------
__global__ __launch_bounds__(256) void part(
    const int* __restrict__ src, const int* __restrict__ dst,
    int* __restrict__ curD, int* __restrict__ curS,
    int* __restrict__ pairs, unsigned char* __restrict__ srcb,
    int E, int NP, int chunk) {
    __shared__ int cD[MAXP];
    __shared__ int cS[MAXP];
    int tid = threadIdx.x;
    int e0 = blockIdx.x * chunk;
    int e1 = min(E, e0 + chunk);
    for (int i = tid; i < NP; i += 256) { cD[i] = 0; cS[i] = 0; }
    __syncthreads();
    // phase 1: local counts (LDS int atomics)
    for (int e = e0 + tid; e < e1; e += 256) {
        int d = dst[e], s = src[e];
        atomicAdd(&cD[d >> 6], 1);
        atomicAdd(&cS[s >> 6], 1);
    }
    __syncthreads();
    // phase 2: bulk reservation (few global atomics), cursor := my base
    for (int b = tid; b < NP; b += 256) {
        int c = cD[b];
        cD[b] = c ? atomicAdd(&curD[b], c) : 0;
        c = cS[b];
        cS[b] = c ? atomicAdd(&curS[b], c) : 0;
    }
    __syncthreads();
    // phase 3: re-rank via LDS cursors, scatter into exact slots
    for (int e = e0 + tid; e < e1; e += 256) {
        int d = dst[e], s = src[e];
        int pd = d >> 6, ps = s >> 6;
        int slot = atomicAdd(&cD[pd], 1);
        if (slot < CAPE) pairs[pd * CAPE + slot] = (s << 6) | (d & 63);
        int slot2 = atomicAdd(&cS[ps], 1);
        if (slot2 < CAPS) srcb[(size_t)ps * CAPS + slot2] = (unsigned char)(s & 63);
    }
}

// ---------------- deg: per-partition out-degree histogram -> oscale ---------
__global__ __launch_bounds__(256) void deg(
    const int* __restrict__ curS, const unsigned char* __restrict__ srcb,
    float* __restrict__ oscale, int N) {
    __shared__ int hist[PN];
    int p = blockIdx.x, tid = threadIdx.x;
    if (tid < PN) hist[tid] = 0;
    __syncthreads();
    int cnt = min(curS[p], CAPS);
    const unsigned char* b = &srcb[(size_t)p * CAPS];
    for (int i = tid; i < cnt; i += 256) atomicAdd(&hist[b[i]], 1);
    __syncthreads();
    if (tid < PN) {
        int node = p * PN + tid;
        if (node < N) oscale[node] = rsqrtf((float)max(hist[tid], 1));
    }
}

// ---------------- h = (feat * outdeg^-1/2) @ W  (bf16, lane-permuted) -------
// 32 rows x 128 cols per block, 256 threads, 4x4 per thread, BK=32.
// h row layout: position 4*l+k holds element l+32k (l=0..31,k=0..3).
__global__ __launch_bounds__(256) void gemm_h(
    const float* __restrict__ feat, const float* __restrict__ W,
    const float* __restrict__ oscale, ushortT* __restrict__ h, int M) {
    __shared__ float As[32][36];
    __shared__ float Bs[32][128];

    int tid = threadIdx.x;
    int m0 = blockIdx.x * 32;
    int tx = tid & 31;
    int ty = tid >> 5;
    int bc = tx << 2;

    float acc[4][4];
#pragma unroll
    for (int r = 0; r < 4; ++r)
#pragma unroll
        for (int c = 0; c < 4; ++c) acc[r][c] = 0.f;

    int am = tid >> 3;
    int ak = (tid & 7) << 2;
    int arow = m0 + am;
    float scale = (arow < M) ? oscale[arow] : 0.f;

    for (int k0 = 0; k0 < DIM; k0 += 32) {
        float4 a = make_float4(0.f, 0.f, 0.f, 0.f);
        if (arow < M) a = *(const float4*)&feat[(size_t)arow * DIM + k0 + ak];
        As[ak + 0][am] = a.x * scale;
        As[ak + 1][am] = a.y * scale;
        As[ak + 2][am] = a.z * scale;
        As[ak + 3][am] = a.w * scale;
#pragma unroll
        for (int i = 0; i < 4; ++i) {
            int k = ty + i * 8;
            *(float4*)&Bs[k][bc] = *(const float4*)&W[(size_t)(k0 + k) * DIM + bc];
        }
        __syncthreads();
#pragma unroll
        for (int k = 0; k < 32; ++k) {
            float4 a4 = *(const float4*)&As[k][ty << 2];
            float4 b4 = *(const float4*)&Bs[k][bc];
            acc[0][0] += a4.x * b4.x; acc[0][1] += a4.x * b4.y; acc[0][2] += a4.x * b4.z; acc[0][3] += a4.x * b4.w;
            acc[1][0] += a4.y * b4.x; acc[1][1] += a4.y * b4.y; acc[1][2] += a4.y * b4.z; acc[1][3] += a4.y * b4.w;
            acc[2][0] += a4.z * b4.x; acc[2][1] += a4.z * b4.y; acc[2][2] += a4.z * b4.z; acc[2][3] += a4.z * b4.w;
            acc[3][0] += a4.w * b4.x; acc[3][1] += a4.w * b4.y; acc[3][2] += a4.w * b4.z; acc[3][3] += a4.w * b4.w;
        }
        __syncthreads();
    }
    // epilogue: stage tile in LDS (reuse Bs), emit bf16 permuted rows
    float* T = &Bs[0][0];
#pragma unroll
    for (int r = 0; r < 4; ++r)
#pragma unroll
        for (int j = 0; j < 4; ++j)
            T[((ty << 2) + r) * 128 + bc + j] = acc[r][j];
    __syncthreads();
    for (int q = tid; q < 1024; q += 256) {
        int row = q >> 5, l = q & 31;
        int m = m0 + row;
        if (m < M) {
            ushort4 v;
            v.x = f2bf(T[row * 128 + l]);
            v.y = f2bf(T[row * 128 + l + 32]);
            v.z = f2bf(T[row * 128 + l + 64]);
            v.w = f2bf(T[row * 128 + l + 96]);
            *(ushort4*)&h[(size_t)m * DIM + (l << 2)] = v;
        }
    }
}

// ---------------- aggp: in-LDS counting sort + REGISTER accumulation --------
// One block (512 thr) per dst-partition. Int LDS atomics only (cheap).
// Each half-wave owns nodes hw, hw+16, hw+32, hw+48 and register-accumulates.
__global__ __launch_bounds__(PULL_T) void aggp(
    const ushortT* __restrict__ h, const int* __restrict__ pairs,
    const int* __restrict__ curD, float* __restrict__ out, int N) {
    __shared__ int ep[CAPE];       // raw packed pairs
    __shared__ int sorted[CAPE];   // src ids sorted by local dst
    __shared__ int hist[PN];
    __shared__ int offs[PN];
    __shared__ int cur[PN];
    int p = blockIdx.x, tid = threadIdx.x;
    int cnt = min(curD[p], CAPE);
    if (tid < PN) hist[tid] = 0;
    __syncthreads();
    const int* pb = &pairs[(size_t)p * CAPE];
    for (int i = tid; i < cnt; i += PULL_T) {
        int w = pb[i];
        ep[i] = w;
        atomicAdd(&hist[w & 63], 1);
    }
    __syncthreads();
    if (tid < PN) {   // wave 0 exactly: 64-lane exclusive shuffle-scan
        int x = hist[tid];
        int incl = x;
        for (int o = 1; o < 64; o <<= 1) {
            int y = __shfl_up(incl, o, 64);
            if (tid >= o) incl += y;
        }
        offs[tid] = incl - x;
        cur[tid] = incl - x;
    }
    __syncthreads();
    for (int i = tid; i < cnt; i += PULL_T) {
        int w = ep[i];
        int slot = atomicAdd(&cur[w & 63], 1);
        sorted[slot] = w >> 6;
    }
    __syncthreads();
    int hw = tid >> 5;          // 0..15
    int l = tid & 31;
    for (int nd = hw; nd < PN; nd += 16) {      // uniform per half-wave
        int node = p * PN + nd;
        if (node >= N) continue;
        int start = offs[nd];
        int degn = hist[nd];
        float a0 = 0.f, a1 = 0.f, a2 = 0.f, a3 = 0.f;
        int e = 0;
        for (; e + 4 <= degn; e += 4) {
            int s0 = sorted[start + e];
            int s1 = sorted[start + e + 1];
            int s2 = sorted[start + e + 2];
            int s3 = sorted[start + e + 3];
            ushort4 v0 = *(const ushort4*)&h[(size_t)s0 * DIM + (l << 2)];
            ushort4 v1 = *(const ushort4*)&h[(size_t)s1 * DIM + (l << 2)];
            ushort4 v2 = *(const ushort4*)&h[(size_t)s2 * DIM + (l << 2)];
            ushort4 v3 = *(const ushort4*)&h[(size_t)s3 * DIM + (l << 2)];
            a0 += (bf2f(v0.x) + bf2f(v1.x)) + (bf2f(v2.x) + bf2f(v3.x));
            a1 += (bf2f(v0.y) + bf2f(v1.y)) + (bf2f(v2.y) + bf2f(v3.y));
            a2 += (bf2f(v0.z) + bf2f(v1.z)) + (bf2f(v2.z) + bf2f(v3.z));
            a3 += (bf2f(v0.w) + bf2f(v1.w)) + (bf2f(v2.w) + bf2f(v3.w));
        }
        for (; e < degn; ++e) {
            int s0 = sorted[start + e];
            ushort4 v0 = *(const ushort4*)&h[(size_t)s0 * DIM + (l << 2)];
            a0 += bf2f(v0.x); a1 += bf2f(v0.y);
            a2 += bf2f(v0.z); a3 += bf2f(v0.w);
        }
        float sc = rsqrtf((float)max(degn, 1));
        size_t ob = (size_t)node * DIM;
        out[ob + l]      = a0 * sc;    // un-permute: lane l holds dims
        out[ob + l + 32] = a1 * sc;    // l, l+32, l+64, l+96
        out[ob + l + 64] = a2 * sc;
        out[ob + l + 96] = a3 * sc;
    }
}

extern "C" void kernel_launch(void* const* d_in, const int* in_sizes, int n_in,
                              void* d_out, int out_size, void* d_ws, size_t ws_size,
                              hipStream_t stream) {
    const float* feat = (const float*)d_in[0];
    const float* W    = (const float*)d_in[1];
    const int*   src  = (const int*)d_in[2];
    const int*   dst  = (const int*)d_in[3];
    float* out = (float*)d_out;

    int N = in_sizes[0] / DIM;       // 100000
    int E = in_sizes[2];             // 1.6M
    int NP = (N + PN - 1) / PN;      // 1563 (<= MAXP)

    // workspace layout
    int* curD = (int*)d_ws;                       // NP
    int* curS = curD + NP;                        // NP
    float* oscale = (float*)(curS + NP);          // N
    int* pairs = (int*)(oscale + N);              // NP*CAPE
    unsigned char* srcb = (unsigned char*)(pairs + (size_t)NP * CAPE);  // NP*CAPS
    uintptr_t hp = (uintptr_t)(srcb + (size_t)NP * CAPS);
    ushortT* h = (ushortT*)((hp + 15) & ~(uintptr_t)15);  // N*DIM bf16

    hipMemsetAsync(curD, 0, (size_t)2 * NP * sizeof(int), stream);

    int chunk = (E + NB_PART - 1) / NB_PART;
    part<<<NB_PART, 256, 0, stream>>>(src, dst, curD, curS, pairs, srcb, E, NP, chunk);
    deg<<<NP, 256, 0, stream>>>(curS, srcb, oscale, N);
    gemm_h<<<(N + 31) / 32, 256, 0, stream>>>(feat, W, oscale, h, N);
    aggp<<<NP, PULL_T, 0, stream>>>(h, pairs, curD, out, N);
}

// Round 5
// 274.054 us; speedup vs baseline: 5.0595x; 1.0367x over previous
//
#include <hip/hip_runtime.h>
#include <stdint.h>

// GraphConv: out = indeg^-1/2 * segsum_dst( (feat * outdeg^-1/2)[src] ) @ W
// Transform-first: h = (feat*outdeg^-1/2) @ W once (bf16, lane-permuted),
// then aggregate h rows per dst from dst-partitioned edge buckets.
//
// R5: part rewritten. Old part: 4 LDS atomics/edge on 128 blocks + 3.2M
// random 4B/1B global scatters (~100MB line-RMW) ~= 140us. New part:
// phase-1 atomicAdd return value IS the local rank (stashed in regs,
// 13 edges/thread unrolled) -> 2 LDS atomics/edge, no re-rank pass; edges
// staged dst-partition-sorted in LDS and flushed as coalesced runs.
// Partitions 64->128 nodes (NPP=782), 241 blocks -> all CUs busy.

#define DIM 128
#define PN 128            // nodes per dst/src partition
#define MAXPP 800         // >= NPP = ceil(100000/128) = 782
#define CAPE 2560         // edges per dst-partition (mean 2048, +11 sigma)
#define CAPS 2560         // src entries per src-partition
#define PT 512            // part threads
#define EPT 13            // edges per thread in part
#define CHUNK (PT * EPT)  // 6656 edges per part block
#define CAPA 1536         // sorted edges per agg half-partition (mean 1024)

typedef unsigned int uint;
typedef unsigned short ushortT;

__device__ __forceinline__ ushortT f2bf(float x) {
    uint u = __float_as_uint(x);
    u = (u + 0x7FFFu + ((u >> 16) & 1u)) >> 16;   // RNE
    return (ushortT)u;
}
__device__ __forceinline__ float bf2f(ushortT b) {
    return __uint_as_float(((uint)b) << 16);
}

// ---------------- part: partition edges by dst>>7 (+ src bytes by src>>7) ---
__global__ __launch_bounds__(PT) void part(
    const int* __restrict__ src, const int* __restrict__ dst,
    int* __restrict__ curD, int* __restrict__ curS,
    int* __restrict__ pairs, unsigned char* __restrict__ srcb,
    int E, int NPP) {
    __shared__ int cD[MAXPP], cS[MAXPP];
    __shared__ int lofD[MAXPP], lofS[MAXPP];     // local exclusive offsets
    __shared__ int gbD[MAXPP], gbS[MAXPP];       // global base per partition
    __shared__ int bufD[CHUNK];                  // dst-sorted packed words
    __shared__ unsigned char bufS[CHUNK];        // src-sorted local bytes

    int tid = threadIdx.x;
    long long base = (long long)blockIdx.x * CHUNK;
    for (int i = tid; i < NPP; i += PT) { cD[i] = 0; cS[i] = 0; }
    __syncthreads();

    // P1: count; atomicAdd return value = unique local rank (stash in regs)
    int sv[EPT], dv[EPT], lrD[EPT], lrS[EPT];
#pragma unroll
    for (int j = 0; j < EPT; ++j) {
        long long e = base + tid + j * PT;
        bool ok = e < E;
        int s = 0, d = 0;
        if (ok) { s = src[e]; d = dst[e]; }
        sv[j] = s; dv[j] = d;
        lrD[j] = ok ? atomicAdd(&cD[d >> 7], 1) : 0;
        lrS[j] = ok ? atomicAdd(&cS[s >> 7], 1) : 0;
    }
    __syncthreads();

    // P2: block-local exclusive scans (Hillis-Steele over 1024, bufD scratch)
    int* sc = bufD;
    for (int pass = 0; pass < 2; ++pass) {
        const int* cnts = pass ? cS : cD;
        int* lof = pass ? lofS : lofD;
        for (int i = tid; i < 1024; i += PT) sc[i] = (i < NPP) ? cnts[i] : 0;
        __syncthreads();
        for (int off = 1; off < 1024; off <<= 1) {
            int i0 = tid, i1 = tid + PT;
            int a0 = (i0 >= off) ? sc[i0 - off] : 0;
            int a1 = (i1 >= off) ? sc[i1 - off] : 0;
            __syncthreads();
            sc[i0] += a0; sc[i1] += a1;
            __syncthreads();
        }
        for (int i = tid; i < NPP; i += PT) lof[i] = sc[i] - cnts[i];
        __syncthreads();
    }

    // P2b: bulk global reservations (~2*NPP atomics per block)
    for (int i = tid; i < NPP; i += PT) {
        int c = cD[i];
        gbD[i] = c ? atomicAdd(&curD[i], c) : 0;
        c = cS[i];
        gbS[i] = c ? atomicAdd(&curS[i], c) : 0;
    }

    // P3: place edges into LDS at sorted positions (no atomics)
#pragma unroll
    for (int j = 0; j < EPT; ++j) {
        long long e = base + tid + j * PT;
        if (e < E) {
            int s = sv[j], d = dv[j];
            bufD[lofD[d >> 7] + lrD[j]] = (s << 7) | (d & 127);
            bufS[lofS[s >> 7] + lrS[j]] = (unsigned char)(s & 127);
        }
    }
    __syncthreads();

    // P4: coalesced run flush; partition of index i via binary search in lof
    int cnt = (int)(((long long)E - base < (long long)CHUNK) ? (E - base) : CHUNK);
    for (int i = tid; i < cnt; i += PT) {
        int lo = 0, hi = NPP - 1;
        while (lo < hi) { int mid = (lo + hi + 1) >> 1; if (lofD[mid] <= i) lo = mid; else hi = mid - 1; }
        int pos = gbD[lo] + (i - lofD[lo]);
        if (pos < CAPE) pairs[(size_t)lo * CAPE + pos] = bufD[i];
    }
    for (int i = tid; i < cnt; i += PT) {
        int lo = 0, hi = NPP - 1;
        while (lo < hi) { int mid = (lo + hi + 1) >> 1; if (lofS[mid] <= i) lo = mid; else hi = mid - 1; }
        int pos = gbS[lo] + (i - lofS[lo]);
        if (pos < CAPS) srcb[(size_t)lo * CAPS + pos] = bufS[i];
    }
}

// ---------------- deg: per-partition out-degree histogram -> oscale ---------
__global__ __launch_bounds__(256) void deg(
    const int* __restrict__ curS, const unsigned char* __restrict__ srcb,
    float* __restrict__ oscale, int N) {
    __shared__ int hist[PN];
    int p = blockIdx.x, tid = threadIdx.x;
    if (tid < PN) hist[tid] = 0;
    __syncthreads();
    int cnt = min(curS[p], CAPS);
    const unsigned char* b = &srcb[(size_t)p * CAPS];
    for (int i = tid; i < cnt; i += 256) atomicAdd(&hist[b[i]], 1);
    __syncthreads();
    if (tid < PN) {
        int node = p * PN + tid;
        if (node < N) oscale[node] = rsqrtf((float)max(hist[tid], 1));
    }
}

// ---------------- h = (feat * outdeg^-1/2) @ W  (bf16, lane-permuted) -------
// h row layout: position 4*l+k holds element l+32k (l=0..31,k=0..3).
__global__ __launch_bounds__(256) void gemm_h(
    const float* __restrict__ feat, const float* __restrict__ W,
    const float* __restrict__ oscale, ushortT* __restrict__ h, int M) {
    __shared__ float As[32][36];
    __shared__ float Bs[32][128];

    int tid = threadIdx.x;
    int m0 = blockIdx.x * 32;
    int tx = tid & 31;
    int ty = tid >> 5;
    int bc = tx << 2;

    float acc[4][4];
#pragma unroll
    for (int r = 0; r < 4; ++r)
#pragma unroll
        for (int c = 0; c < 4; ++c) acc[r][c] = 0.f;

    int am = tid >> 3;
    int ak = (tid & 7) << 2;
    int arow = m0 + am;
    float scale = (arow < M) ? oscale[arow] : 0.f;

    for (int k0 = 0; k0 < DIM; k0 += 32) {
        float4 a = make_float4(0.f, 0.f, 0.f, 0.f);
        if (arow < M) a = *(const float4*)&feat[(size_t)arow * DIM + k0 + ak];
        As[ak + 0][am] = a.x * scale;
        As[ak + 1][am] = a.y * scale;
        As[ak + 2][am] = a.z * scale;
        As[ak + 3][am] = a.w * scale;
#pragma unroll
        for (int i = 0; i < 4; ++i) {
            int k = ty + i * 8;
            *(float4*)&Bs[k][bc] = *(const float4*)&W[(size_t)(k0 + k) * DIM + bc];
        }
        __syncthreads();
#pragma unroll
        for (int k = 0; k < 32; ++k) {
            float4 a4 = *(const float4*)&As[k][ty << 2];
            float4 b4 = *(const float4*)&Bs[k][bc];
            acc[0][0] += a4.x * b4.x; acc[0][1] += a4.x * b4.y; acc[0][2] += a4.x * b4.z; acc[0][3] += a4.x * b4.w;
            acc[1][0] += a4.y * b4.x; acc[1][1] += a4.y * b4.y; acc[1][2] += a4.y * b4.z; acc[1][3] += a4.y * b4.w;
            acc[2][0] += a4.z * b4.x; acc[2][1] += a4.z * b4.y; acc[2][2] += a4.z * b4.z; acc[2][3] += a4.z * b4.w;
            acc[3][0] += a4.w * b4.x; acc[3][1] += a4.w * b4.y; acc[3][2] += a4.w * b4.z; acc[3][3] += a4.w * b4.w;
        }
        __syncthreads();
    }
    float* T = &Bs[0][0];
#pragma unroll
    for (int r = 0; r < 4; ++r)
#pragma unroll
        for (int j = 0; j < 4; ++j)
            T[((ty << 2) + r) * 128 + bc + j] = acc[r][j];
    __syncthreads();
    for (int q = tid; q < 1024; q += 256) {
        int row = q >> 5, l = q & 31;
        int m = m0 + row;
        if (m < M) {
            ushort4 v;
            v.x = f2bf(T[row * 128 + l]);
            v.y = f2bf(T[row * 128 + l + 32]);
            v.z = f2bf(T[row * 128 + l + 64]);
            v.w = f2bf(T[row * 128 + l + 96]);
            *(ushort4*)&h[(size_t)m * DIM + (l << 2)] = v;
        }
    }
}

// ---------------- aggp: in-LDS counting sort + register accumulation --------
// 2 blocks per 128-node partition (64 nodes each), 256 threads, 7KB LDS
// -> 8 blocks/CU resident. Int LDS atomics only; gathers unrolled 8-deep.
__global__ __launch_bounds__(256) void aggp(
    const ushortT* __restrict__ h, const int* __restrict__ pairs,
    const int* __restrict__ curD, float* __restrict__ out, int N) {
    __shared__ int sorted[CAPA];
    __shared__ int hist[64], offs[64], cur[64];
    int b = blockIdx.x;
    int p = b >> 1, sub = b & 1;
    int tid = threadIdx.x;
    if (tid < 64) hist[tid] = 0;
    __syncthreads();
    int cnt = min(curD[p], CAPE);
    const int* pb = &pairs[(size_t)p * CAPE];
    for (int i = tid; i < cnt; i += 256) {
        int dl = pb[i] & 127;
        if ((dl >> 6) == sub) atomicAdd(&hist[dl & 63], 1);
    }
    __syncthreads();
    if (tid < 64) {   // wave 0: 64-lane exclusive shuffle-scan
        int x = hist[tid], incl = x;
        for (int o = 1; o < 64; o <<= 1) {
            int y = __shfl_up(incl, o, 64);
            if (tid >= o) incl += y;
        }
        offs[tid] = incl - x;
        cur[tid] = incl - x;
    }
    __syncthreads();
    for (int i = tid; i < cnt; i += 256) {
        int w = pb[i];
        int dl = w & 127;
        if ((dl >> 6) == sub) {
            int slot = atomicAdd(&cur[dl & 63], 1);
            if (slot < CAPA) sorted[slot] = w >> 7;
        }
    }
    __syncthreads();
    int hw = tid >> 5, l = tid & 31;
    for (int nd = hw; nd < 64; nd += 8) {
        int node = p * PN + sub * 64 + nd;
        if (node >= N) continue;
        int start = offs[nd];
        int degn = hist[nd];
        int end = min(start + degn, CAPA);
        float a0 = 0.f, a1 = 0.f, a2 = 0.f, a3 = 0.f;
        int e = start;
        for (; e + 8 <= end; e += 8) {
            int s0 = sorted[e],     s1 = sorted[e + 1];
            int s2 = sorted[e + 2], s3 = sorted[e + 3];
            int s4 = sorted[e + 4], s5 = sorted[e + 5];
            int s6 = sorted[e + 6], s7 = sorted[e + 7];
            ushort4 v0 = *(const ushort4*)&h[(size_t)s0 * DIM + (l << 2)];
            ushort4 v1 = *(const ushort4*)&h[(size_t)s1 * DIM + (l << 2)];
            ushort4 v2 = *(const ushort4*)&h[(size_t)s2 * DIM + (l << 2)];
            ushort4 v3 = *(const ushort4*)&h[(size_t)s3 * DIM + (l << 2)];
            ushort4 v4 = *(const ushort4*)&h[(size_t)s4 * DIM + (l << 2)];
            ushort4 v5 = *(const ushort4*)&h[(size_t)s5 * DIM + (l << 2)];
            ushort4 v6 = *(const ushort4*)&h[(size_t)s6 * DIM + (l << 2)];
            ushort4 v7 = *(const ushort4*)&h[(size_t)s7 * DIM + (l << 2)];
            a0 += ((bf2f(v0.x) + bf2f(v1.x)) + (bf2f(v2.x) + bf2f(v3.x))) +
                  ((bf2f(v4.x) + bf2f(v5.x)) + (bf2f(v6.x) + bf2f(v7.x)));
            a1 += ((bf2f(v0.y) + bf2f(v1.y)) + (bf2f(v2.y) + bf2f(v3.y))) +
                  ((bf2f(v4.y) + bf2f(v5.y)) + (bf2f(v6.y) + bf2f(v7.y)));
            a2 += ((bf2f(v0.z) + bf2f(v1.z)) + (bf2f(v2.z) + bf2f(v3.z))) +
                  ((bf2f(v4.z) + bf2f(v5.z)) + (bf2f(v6.z) + bf2f(v7.z)));
            a3 += ((bf2f(v0.w) + bf2f(v1.w)) + (bf2f(v2.w) + bf2f(v3.w))) +
                  ((bf2f(v4.w) + bf2f(v5.w)) + (bf2f(v6.w) + bf2f(v7.w)));
        }
        for (; e < end; ++e) {
            int s0 = sorted[e];
            ushort4 v0 = *(const ushort4*)&h[(size_t)s0 * DIM + (l << 2)];
            a0 += bf2f(v0.x); a1 += bf2f(v0.y);
            a2 += bf2f(v0.z); a3 += bf2f(v0.w);
        }
        float scn = rsqrtf((float)max(degn, 1));
        size_t ob = (size_t)node * DIM;
        out[ob + l]      = a0 * scn;   // un-permute: lane l holds dims
        out[ob + l + 32] = a1 * scn;   // l, l+32, l+64, l+96
        out[ob + l + 64] = a2 * scn;
        out[ob + l + 96] = a3 * scn;
    }
}

extern "C" void kernel_launch(void* const* d_in, const int* in_sizes, int n_in,
                              void* d_out, int out_size, void* d_ws, size_t ws_size,
                              hipStream_t stream) {
    const float* feat = (const float*)d_in[0];
    const float* W    = (const float*)d_in[1];
    const int*   src  = (const int*)d_in[2];
    const int*   dst  = (const int*)d_in[3];
    float* out = (float*)d_out;

    int N = in_sizes[0] / DIM;        // 100000
    int E = in_sizes[2];              // 1.6M
    int NPP = (N + PN - 1) / PN;      // 782 (<= MAXPP)

    // workspace layout
    int* curD = (int*)d_ws;                       // NPP
    int* curS = curD + NPP;                       // NPP
    float* oscale = (float*)(curS + NPP);         // N
    int* pairs = (int*)(oscale + N);              // NPP*CAPE
    unsigned char* srcb = (unsigned char*)(pairs + (size_t)NPP * CAPE);  // NPP*CAPS
    uintptr_t hp = (uintptr_t)(srcb + (size_t)NPP * CAPS);
    ushortT* h = (ushortT*)((hp + 15) & ~(uintptr_t)15);  // N*DIM bf16

    hipMemsetAsync(curD, 0, (size_t)2 * NPP * sizeof(int), stream);

    int nb = (E + CHUNK - 1) / CHUNK;   // 241
    part<<<nb, PT, 0, stream>>>(src, dst, curD, curS, pairs, srcb, E, NPP);
    deg<<<NPP, 256, 0, stream>>>(curS, srcb, oscale, N);
    gemm_h<<<(N + 31) / 32, 256, 0, stream>>>(feat, W, oscale, h, N);
    aggp<<<2 * NPP, 256, 0, stream>>>(h, pairs, curD, out, N);
}